// Round 9
// baseline (221.377 us; speedup 1.0000x reference)
//
#include <hip/hip_runtime.h>
#include <math.h>

typedef _Float16 h2_t __attribute__((ext_vector_type(2)));
typedef _Float16 h4_t __attribute__((ext_vector_type(4)));
typedef _Float16 h8_t __attribute__((ext_vector_type(8)));

#define NP 32
#define KC 31
#define HH 512
#define WW 512
#define BB 4
#define CC 3

#define TXO 64        // R9: 64-wide tile, 8 outputs/thread in x (halves LDS reads/output)
#define TYO 32
#define TROWS 62      // 32 outputs + 15 + 15 halo
#define TWORDS 48     // tile row STRIDE in h2 words (%32==16 -> uniform 2-way = free)
#define TLW 48        // words staged per row (words 0..46 needed)
#define TILEW (TROWS * TWORDS)
#define WSTR 36       // weight table plane stride in half2-words

// Packed per-plane 1D Gaussian taps, phase A = (g[2m],g[2m+1]), phase B = (g[2m-1],g[2m]).
// NOTE (R4/R5): weight gen stays in this separate kernel; grid z stays BB.
// NOTE (R7): don't shrink tiles. NOTE (R8): barriers/conflicts are not the
// limiter — the per-CU LDS issue pipe is; this round cuts reads/output ~1.8x.
__device__ h2_t g_wtabh[NP * WSTR];

__global__ void init_wtab_kernel() {
    const int tid = threadIdx.x;          // 0..1023
    const int p = tid >> 5;               // plane
    const int t = tid & 31;               // padded tap position 0..31 (g[31]==0)
    const double stepd = 50.0 / 31.0;
    double coc = (p < 31) ? (double)p * stepd : 50.0;   // numpy linspace semantics
    float gt;
    if (coc < 0.5) {
        gt = (t == 15) ? 1.f : 0.f;       // identity plane (plane 0 only)
    } else {
        double sigma = coc / 2.355;
        int k = (int)(2.0 * coc + 1.0);   // trunc, matches python int()
        if ((k & 1) == 0) k += 1;
        if (k > KC) k = KC;
        int h = k / 2;
        int d = t - 15;
        float denom = (float)(2.0 * sigma * sigma);
        float v = (d >= -h && d <= h && t < KC) ? expf(-(float)(d * d) / denom) : 0.f;
        float s = v;
        #pragma unroll
        for (int off = 1; off < 32; off <<= 1) s += __shfl_xor(s, off, 32);
        gt = v / s;
    }
    const int m = t & 15;
    const int s0 = (t < 16) ? (2 * m) : ((2 * m - 1 < 0) ? 0 : 2 * m - 1);
    const int s1 = (t < 16) ? (2 * m + 1) : (2 * m);
    float w0 = __shfl(gt, s0, 32);
    float w1 = __shfl(gt, s1, 32);
    if (t >= 16 && (2 * m - 1) < 0) w0 = 0.f;   // g[-1] = 0
    h2_t w; w.x = (_Float16)w0; w.y = (_Float16)w1;
    g_wtabh[p * WSTR + t] = w;
    if (t < WSTR - 32) {
        h2_t z; z.x = (_Float16)0.f; z.y = (_Float16)0.f;
        g_wtabh[p * WSTR + 32 + t] = z;
    }
}

__device__ __forceinline__ double plane_of(int i) {
    const double stepd = 50.0 / 31.0;
    return (i < 31) ? (double)i * stepd : 50.0;
}

// (256,2): 256-VGPR cap for wj[8][16] (~128 regs) + loop state (~70). 2 waves/SIMD,
// 2 blocks/CU (LDS 40.3 KB). Spill tripwire: WRITE_SIZE must stay ~12.3 MB.
__launch_bounds__(256, 2)
__global__ void defocus_kernel(const float* __restrict__ img,
                               const float* __restrict__ coc,
                               float* __restrict__ out) {
    const int tx = threadIdx.x;            // 0..7
    const int ty = threadIdx.y;            // 0..31
    const int tid = ty * 8 + tx;
    const int tilex = blockIdx.x * TXO;
    const int tiley = blockIdx.y * TYO;
    const int b = blockIdx.z;

    __shared__ __align__(16) h2_t wtab[NP * WSTR];
    __shared__ __align__(16) h2_t tiles[CC * TILEW];

    // stage weight table (global -> LDS)
    for (int f = tid; f < NP * WSTR; f += 256) wtab[f] = g_wtabh[f];

    // stage ALL 3 channel tiles up front (single barrier total)
    #pragma unroll
    for (int c = 0; c < CC; ++c) {
        const float* src = img + (size_t)(b * CC + c) * HH * WW;
        h2_t* tc = &tiles[c * TILEW];
        for (int f = tid; f < TROWS * TLW; f += 256) {
            int r = f / TLW;
            int w = f - r * TLW;
            int gy = tiley - 15 + r;
            int gx = tilex - 15 + 2 * w;
            float v0 = 0.f, v1 = 0.f;
            if ((unsigned)gy < (unsigned)HH) {
                if ((unsigned)gx < (unsigned)WW) v0 = src[gy * WW + gx];
                if ((unsigned)(gx + 1) < (unsigned)WW) v1 = src[gy * WW + gx + 1];
            }
            h2_t pv; pv.x = (_Float16)v0; pv.y = (_Float16)v1;
            tc[r * TWORDS + w] = pv;
        }
    }

    const int yo = tiley + ty;
    const int xo = tilex + tx * 8;

    // per-pixel bin index for 8 pixels, exact double-precision boundary semantics
    const float4 cv0 = *(const float4*)&coc[((size_t)b * HH + yo) * WW + xo];
    const float4 cv1 = *(const float4*)&coc[((size_t)b * HH + yo) * WW + xo + 4];
    const float cocf[8] = {cv0.x, cv0.y, cv0.z, cv0.w, cv1.x, cv1.y, cv1.z, cv1.w};
    int idx[8];
    #pragma unroll
    for (int j = 0; j < 8; ++j) {
        const double stepd = 50.0 / 31.0;
        double cd = (double)cocf[j];
        int i0 = (int)floor(cd / stepd + 0.5);
        i0 = min(max(i0, 0), 31);
        if (i0 > 0 && cd <= 0.5 * (plane_of(i0 - 1) + plane_of(i0))) {
            i0 -= 1;
        } else if (i0 < 31 && cd > 0.5 * (plane_of(i0) + plane_of(i0 + 1))) {
            i0 += 1;
        }
        idx[j] = i0;
    }

    __syncthreads();  // the ONLY barrier: wtab + all tiles staged

    // gather 8 weight rows into registers; even j: phase A, odd j: phase B
    h2_t wj[8][16];
    #pragma unroll
    for (int j = 0; j < 8; ++j) {
        const h2_t* wp = &wtab[idx[j] * WSTR + (j & 1) * 16];
        #pragma unroll
        for (int m = 0; m < 4; ++m) {
            h8_t v = *(const h8_t*)(wp + 4 * m);   // 16B aligned: WSTR%4==0
            #pragma unroll
            for (int q = 0; q < 4; ++q) {
                h2_t t; t.x = v[2 * q]; t.y = v[2 * q + 1];
                wj[j][4 * m + q] = t;
            }
        }
    }

    // runtime c-loop; dy fully unrolled inside (static wj column-tap indices).
    for (int c = 0; c < CC; ++c) {
        float acc[8];
        #pragma unroll
        for (int j = 0; j < 8; ++j) acc[j] = 0.f;
        const h2_t* rowbase = &tiles[c * TILEW + ty * TWORDS + 4 * tx];
        #pragma unroll
        for (int dy = 0; dy < KC; ++dy) {
            const h2_t* rp = rowbase + dy * TWORDS;
            h2_t rw[20];
            #pragma unroll
            for (int m = 0; m < 10; ++m) {
                h4_t q = *(const h4_t*)(rp + 2 * m);   // ds_read_b64, 2-way-free banks
                h2_t lo; lo.x = q[0]; lo.y = q[1];
                h2_t hi; hi.x = q[2]; hi.y = q[3];
                rw[2 * m]     = lo;
                rw[2 * m + 1] = hi;
            }
            float rs[8];
            #pragma unroll
            for (int j = 0; j < 8; ++j) rs[j] = 0.f;
            #pragma unroll
            for (int m = 0; m < 16; ++m) {
                rs[0] = __builtin_amdgcn_fdot2(wj[0][m], rw[m],     rs[0], false);
                rs[1] = __builtin_amdgcn_fdot2(wj[1][m], rw[m],     rs[1], false);
                rs[2] = __builtin_amdgcn_fdot2(wj[2][m], rw[m + 1], rs[2], false);
                rs[3] = __builtin_amdgcn_fdot2(wj[3][m], rw[m + 1], rs[3], false);
                rs[4] = __builtin_amdgcn_fdot2(wj[4][m], rw[m + 2], rs[4], false);
                rs[5] = __builtin_amdgcn_fdot2(wj[5][m], rw[m + 2], rs[5], false);
                rs[6] = __builtin_amdgcn_fdot2(wj[6][m], rw[m + 3], rs[6], false);
                rs[7] = __builtin_amdgcn_fdot2(wj[7][m], rw[m + 3], rs[7], false);
            }
            // column taps g[dy] at static register indices
            #pragma unroll
            for (int j = 0; j < 8; ++j) {
                float cw;
                if ((j & 1) == 0) {   // phase A
                    cw = ((dy & 1) == 0) ? (float)wj[j][dy >> 1].x
                                         : (float)wj[j][dy >> 1].y;
                } else {              // phase B
                    cw = ((dy & 1) == 0) ? (float)wj[j][dy >> 1].y
                                         : (float)wj[j][(dy + 1) >> 1].x;
                }
                acc[j] += cw * rs[j];
            }
        }

        float* op = &out[((size_t)(b * CC + c) * HH + yo) * WW + xo];
        *(float4*)op       = make_float4(acc[0], acc[1], acc[2], acc[3]);
        *(float4*)(op + 4) = make_float4(acc[4], acc[5], acc[6], acc[7]);
    }
}

extern "C" void kernel_launch(void* const* d_in, const int* in_sizes, int n_in,
                              void* d_out, int out_size, void* d_ws, size_t ws_size,
                              hipStream_t stream) {
    const float* sharp = (const float*)d_in[0];
    const float* cocm  = (const float*)d_in[1];
    float* out = (float*)d_out;

    init_wtab_kernel<<<1, 1024, 0, stream>>>();
    dim3 grid(WW / TXO, HH / TYO, BB);
    dim3 block(8, 32, 1);
    defocus_kernel<<<grid, block, 0, stream>>>(sharp, cocm, out);
}

// Round 10
// 220.876 us; speedup vs baseline: 1.0023x; 1.0023x over previous
//
#include <hip/hip_runtime.h>
#include <math.h>

typedef _Float16 h2_t __attribute__((ext_vector_type(2)));
typedef _Float16 h8_t __attribute__((ext_vector_type(8)));

#define NP 32
#define KC 31
#define HH 512
#define WW 512
#define BB 4
#define CC 3

#define TXO 64        // 8 outputs/thread in x: halves LDS bytes/output (the binding resource)
#define TYO 32
#define TROWS 62      // 32 outputs + 15 + 15 halo
#define TWORDS 48     // tile row STRIDE in h2 words (192 B: b128 quarter-wave = 2-way = free)
#define TLW 47        // words staged per row (halves 0..93 needed)
#define TILEW (TROWS * TWORDS)
#define WSTR 36       // weight table plane stride in half2-words

// Packed per-plane 1D Gaussian taps, phase A = (g[2m],g[2m+1]), phase B = (g[2m-1],g[2m]).
// NOTE (R4/R5): weight gen stays in this separate kernel; grid z stays BB.
// NOTE (R9): a single 512 B wj array defeats SROA and spills wholesale ->
// split into two 256 B arrays (R6-proven size) + amdgpu_waves_per_eu(2,2)
// so the allocator plans for 2 waves/SIMD (256 VGPR) instead of spilling at 128.
__device__ h2_t g_wtabh[NP * WSTR];

__global__ void init_wtab_kernel() {
    const int tid = threadIdx.x;          // 0..1023
    const int p = tid >> 5;               // plane
    const int t = tid & 31;               // padded tap position 0..31 (g[31]==0)
    const double stepd = 50.0 / 31.0;
    double coc = (p < 31) ? (double)p * stepd : 50.0;   // numpy linspace semantics
    float gt;
    if (coc < 0.5) {
        gt = (t == 15) ? 1.f : 0.f;       // identity plane (plane 0 only)
    } else {
        double sigma = coc / 2.355;
        int k = (int)(2.0 * coc + 1.0);   // trunc, matches python int()
        if ((k & 1) == 0) k += 1;
        if (k > KC) k = KC;
        int h = k / 2;
        int d = t - 15;
        float denom = (float)(2.0 * sigma * sigma);
        float v = (d >= -h && d <= h && t < KC) ? expf(-(float)(d * d) / denom) : 0.f;
        float s = v;
        #pragma unroll
        for (int off = 1; off < 32; off <<= 1) s += __shfl_xor(s, off, 32);
        gt = v / s;
    }
    const int m = t & 15;
    const int s0 = (t < 16) ? (2 * m) : ((2 * m - 1 < 0) ? 0 : 2 * m - 1);
    const int s1 = (t < 16) ? (2 * m + 1) : (2 * m);
    float w0 = __shfl(gt, s0, 32);
    float w1 = __shfl(gt, s1, 32);
    if (t >= 16 && (2 * m - 1) < 0) w0 = 0.f;   // g[-1] = 0
    h2_t w; w.x = (_Float16)w0; w.y = (_Float16)w1;
    g_wtabh[p * WSTR + t] = w;
    if (t < WSTR - 32) {
        h2_t z; z.x = (_Float16)0.f; z.y = (_Float16)0.f;
        g_wtabh[p * WSTR + 32 + t] = z;
    }
}

__device__ __forceinline__ double plane_of(int i) {
    const double stepd = 50.0 / 31.0;
    return (i < 31) ? (double)i * stepd : 50.0;
}

// 2 blocks/CU (LDS 40.3 KB, VGPR ~200 @ 2 waves/SIMD). Spill tripwire:
// WRITE_SIZE must stay ~12.3 MB.
__launch_bounds__(256)
__attribute__((amdgpu_waves_per_eu(2, 2)))
__global__ void defocus_kernel(const float* __restrict__ img,
                               const float* __restrict__ coc,
                               float* __restrict__ out) {
    const int tx = threadIdx.x;            // 0..7
    const int ty = threadIdx.y;            // 0..31
    const int tid = ty * 8 + tx;
    const int tilex = blockIdx.x * TXO;
    const int tiley = blockIdx.y * TYO;
    const int b = blockIdx.z;

    __shared__ __align__(16) h2_t wtab[NP * WSTR];
    __shared__ __align__(16) h2_t tiles[CC * TILEW];

    // stage weight table (global -> LDS)
    for (int f = tid; f < NP * WSTR; f += 256) wtab[f] = g_wtabh[f];

    // stage ALL 3 channel tiles up front (single barrier total)
    #pragma unroll
    for (int c = 0; c < CC; ++c) {
        const float* src = img + (size_t)(b * CC + c) * HH * WW;
        h2_t* tc = &tiles[c * TILEW];
        for (int f = tid; f < TROWS * TLW; f += 256) {
            int r = f / TLW;
            int w = f - r * TLW;
            int gy = tiley - 15 + r;
            int gx = tilex - 15 + 2 * w;
            float v0 = 0.f, v1 = 0.f;
            if ((unsigned)gy < (unsigned)HH) {
                if ((unsigned)gx < (unsigned)WW) v0 = src[gy * WW + gx];
                if ((unsigned)(gx + 1) < (unsigned)WW) v1 = src[gy * WW + gx + 1];
            }
            h2_t pv; pv.x = (_Float16)v0; pv.y = (_Float16)v1;
            tc[r * TWORDS + w] = pv;
        }
    }

    const int yo = tiley + ty;
    const int xo = tilex + tx * 8;

    // per-pixel bin index for 8 pixels, exact double-precision boundary semantics
    const float4 cv0 = *(const float4*)&coc[((size_t)b * HH + yo) * WW + xo];
    const float4 cv1 = *(const float4*)&coc[((size_t)b * HH + yo) * WW + xo + 4];
    const float cocf[8] = {cv0.x, cv0.y, cv0.z, cv0.w, cv1.x, cv1.y, cv1.z, cv1.w};
    int idx[8];
    #pragma unroll
    for (int j = 0; j < 8; ++j) {
        const double stepd = 50.0 / 31.0;
        double cd = (double)cocf[j];
        int i0 = (int)floor(cd / stepd + 0.5);
        i0 = min(max(i0, 0), 31);
        if (i0 > 0 && cd <= 0.5 * (plane_of(i0 - 1) + plane_of(i0))) {
            i0 -= 1;
        } else if (i0 < 31 && cd > 0.5 * (plane_of(i0) + plane_of(i0 + 1))) {
            i0 += 1;
        }
        idx[j] = i0;
    }

    __syncthreads();  // the ONLY barrier: wtab + all tiles staged

    // Weight rows in registers. Output j (local window start half = j, rel.
    // word base 4*tx): even j -> phase A, value words rw[m + j/2];
    //                  odd j  -> phase B, value words rw[m + (j-1)/2].
    // Two 256 B arrays (SROA-friendly): wjA[k] = output 2k, wjB[k] = output 2k+1.
    h2_t wjA[4][16];
    h2_t wjB[4][16];
    #pragma unroll
    for (int j = 0; j < 8; ++j) {
        const h2_t* wp = &wtab[idx[j] * WSTR + (j & 1) * 16];  // A at +0, B at +16
        #pragma unroll
        for (int m = 0; m < 4; ++m) {
            h8_t v = *(const h8_t*)(wp + 4 * m);   // 16B aligned: WSTR%4==0
            #pragma unroll
            for (int q = 0; q < 4; ++q) {
                h2_t t; t.x = v[2 * q]; t.y = v[2 * q + 1];
                if ((j & 1) == 0) wjA[j >> 1][4 * m + q] = t;
                else              wjB[j >> 1][4 * m + q] = t;
            }
        }
    }

    // runtime c-loop; dy fully unrolled inside (static wj column-tap indices).
    for (int c = 0; c < CC; ++c) {
        float acc[8];
        #pragma unroll
        for (int j = 0; j < 8; ++j) acc[j] = 0.f;
        const h2_t* rowbase = &tiles[c * TILEW + ty * TWORDS + 4 * tx];  // byte 192ty+16tx: 16B aligned
        #pragma unroll
        for (int dy = 0; dy < KC; ++dy) {
            const h2_t* rp = rowbase + dy * TWORDS;
            h2_t rw[20];
            #pragma unroll
            for (int m = 0; m < 5; ++m) {
                h8_t q = *(const h8_t*)(rp + 4 * m);   // ds_read_b128, 2-way-free banks
                #pragma unroll
                for (int qq = 0; qq < 4; ++qq) {
                    h2_t t; t.x = q[2 * qq]; t.y = q[2 * qq + 1];
                    rw[4 * m + qq] = t;
                }
            }
            float rs[8];
            #pragma unroll
            for (int j = 0; j < 8; ++j) rs[j] = 0.f;
            #pragma unroll
            for (int m = 0; m < 16; ++m) {
                rs[0] = __builtin_amdgcn_fdot2(wjA[0][m], rw[m],     rs[0], false);
                rs[1] = __builtin_amdgcn_fdot2(wjB[0][m], rw[m],     rs[1], false);
                rs[2] = __builtin_amdgcn_fdot2(wjA[1][m], rw[m + 1], rs[2], false);
                rs[3] = __builtin_amdgcn_fdot2(wjB[1][m], rw[m + 1], rs[3], false);
                rs[4] = __builtin_amdgcn_fdot2(wjA[2][m], rw[m + 2], rs[4], false);
                rs[5] = __builtin_amdgcn_fdot2(wjB[2][m], rw[m + 2], rs[5], false);
                rs[6] = __builtin_amdgcn_fdot2(wjA[3][m], rw[m + 3], rs[6], false);
                rs[7] = __builtin_amdgcn_fdot2(wjB[3][m], rw[m + 3], rs[7], false);
            }
            // column taps g[dy] at static register indices
            #pragma unroll
            for (int k = 0; k < 4; ++k) {
                float cwA = ((dy & 1) == 0) ? (float)wjA[k][dy >> 1].x
                                            : (float)wjA[k][dy >> 1].y;
                float cwB = ((dy & 1) == 0) ? (float)wjB[k][dy >> 1].y
                                            : (float)wjB[k][(dy + 1) >> 1].x;
                acc[2 * k]     += cwA * rs[2 * k];
                acc[2 * k + 1] += cwB * rs[2 * k + 1];
            }
        }

        float* op = &out[((size_t)(b * CC + c) * HH + yo) * WW + xo];
        *(float4*)op       = make_float4(acc[0], acc[1], acc[2], acc[3]);
        *(float4*)(op + 4) = make_float4(acc[4], acc[5], acc[6], acc[7]);
    }
}

extern "C" void kernel_launch(void* const* d_in, const int* in_sizes, int n_in,
                              void* d_out, int out_size, void* d_ws, size_t ws_size,
                              hipStream_t stream) {
    const float* sharp = (const float*)d_in[0];
    const float* cocm  = (const float*)d_in[1];
    float* out = (float*)d_out;

    init_wtab_kernel<<<1, 1024, 0, stream>>>();
    dim3 grid(WW / TXO, HH / TYO, BB);
    dim3 block(8, 32, 1);
    defocus_kernel<<<grid, block, 0, stream>>>(sharp, cocm, out);
}

// Round 11
// 138.194 us; speedup vs baseline: 1.6019x; 1.5983x over previous
//
#include <hip/hip_runtime.h>
#include <math.h>

typedef _Float16 h2_t __attribute__((ext_vector_type(2)));
typedef _Float16 h4_t __attribute__((ext_vector_type(4)));
typedef _Float16 h8_t __attribute__((ext_vector_type(8)));

#define NP 32
#define KC 31
#define HH 512
#define WW 512
#define BB 4
#define CC 3

#define TXO 32
#define TYO 32
#define TROWS 62      // 32 outputs + 15 + 15 halo
#define TWORDS 48     // tile row STRIDE in half2-words (%32==16 -> conflict-free, R6-measured 1.0e6)
#define TLW 32        // words STAGED per row (reads touch words 0..31 only)
#define WSTR 36       // weight table plane stride in half2-words

// Packed per-plane 1D Gaussian taps, phase A = (g[2m],g[2m+1]), phase B = (g[2m-1],g[2m]).
// HARD CONSTRAINTS (measured): weight gen stays in this separate kernel (R4);
// grid z stays BB (R4/R5: z=12 variants -> GB-scale scratch traffic); tiles don't
// shrink (R7); >128 VGPRs unobtainable -> RPX stays 4 (R9/R10 both spilled).
__device__ h2_t g_wtabh[NP * WSTR];

__global__ void init_wtab_kernel() {
    const int tid = threadIdx.x;          // 0..1023
    const int p = tid >> 5;               // plane
    const int t = tid & 31;               // padded tap position 0..31 (g[31]==0)
    const double stepd = 50.0 / 31.0;
    double coc = (p < 31) ? (double)p * stepd : 50.0;   // numpy linspace semantics
    float gt;
    if (coc < 0.5) {
        gt = (t == 15) ? 1.f : 0.f;       // identity plane (plane 0 only)
    } else {
        double sigma = coc / 2.355;
        int k = (int)(2.0 * coc + 1.0);   // trunc, matches python int()
        if ((k & 1) == 0) k += 1;
        if (k > KC) k = KC;
        int h = k / 2;
        int d = t - 15;
        float denom = (float)(2.0 * sigma * sigma);
        float v = (d >= -h && d <= h && t < KC) ? expf(-(float)(d * d) / denom) : 0.f;
        float s = v;
        #pragma unroll
        for (int off = 1; off < 32; off <<= 1) s += __shfl_xor(s, off, 32);
        gt = v / s;
    }
    const int m = t & 15;
    const int s0 = (t < 16) ? (2 * m) : ((2 * m - 1 < 0) ? 0 : 2 * m - 1);
    const int s1 = (t < 16) ? (2 * m + 1) : (2 * m);
    float w0 = __shfl(gt, s0, 32);
    float w1 = __shfl(gt, s1, 32);
    if (t >= 16 && (2 * m - 1) < 0) w0 = 0.f;   // g[-1] = 0
    h2_t w; w.x = (_Float16)w0; w.y = (_Float16)w1;
    g_wtabh[p * WSTR + t] = w;
    if (t < WSTR - 32) {
        h2_t z; z.x = (_Float16)0.f; z.y = (_Float16)0.f;
        g_wtabh[p * WSTR + 32 + t] = z;
    }
}

__device__ __forceinline__ double plane_of(int i) {
    const double stepd = 50.0 / 31.0;
    return (i < 31) ? (double)i * stepd : 50.0;
}

// R6 structure exactly; only change: all h2 values are produced by
// __builtin_shufflevector sub-register extracts instead of element inserts
// (hypothesis: element inserts emitted v_perm/v_pack pairs ~doubling VALU).
__launch_bounds__(256, 2)
__global__ void defocus_kernel(const float* __restrict__ img,
                               const float* __restrict__ coc,
                               float* __restrict__ out) {
    const int tx = threadIdx.x;            // 0..7
    const int ty = threadIdx.y;            // 0..31
    const int tid = ty * 8 + tx;
    const int tilex = blockIdx.x * TXO;
    const int tiley = blockIdx.y * TYO;
    const int b = blockIdx.z;

    __shared__ __align__(16) h2_t wtab[NP * WSTR];
    __shared__ __align__(16) h2_t tile[TROWS * TWORDS];

    for (int f = tid; f < NP * WSTR; f += 256) wtab[f] = g_wtabh[f];

    const int yo = tiley + ty;
    const int xo = tilex + tx * 4;

    // per-pixel bin index, exact double-precision boundary semantics
    const float4 cv = *(const float4*)&coc[((size_t)b * HH + yo) * WW + xo];
    const float cocf[4] = {cv.x, cv.y, cv.z, cv.w};
    int idx[4];
    #pragma unroll
    for (int j = 0; j < 4; ++j) {
        const double stepd = 50.0 / 31.0;
        double cd = (double)cocf[j];
        int i0 = (int)floor(cd / stepd + 0.5);
        i0 = min(max(i0, 0), 31);
        if (i0 > 0 && cd <= 0.5 * (plane_of(i0 - 1) + plane_of(i0))) {
            i0 -= 1;
        } else if (i0 < 31 && cd > 0.5 * (plane_of(i0) + plane_of(i0 + 1))) {
            i0 += 1;
        }
        idx[j] = i0;
    }

    __syncthreads();  // wtab staged

    // gather this thread's 4 weight rows into registers
    // even local col (j=0,2): phase A; odd (j=1,3): phase B (pre-shifted by one tap)
    h2_t wj[4][16];
    #pragma unroll
    for (int j = 0; j < 4; ++j) {
        const h2_t* wp = &wtab[idx[j] * WSTR + (j & 1) * 16];
        #pragma unroll
        for (int m = 0; m < 2; ++m) {
            h8_t v = *(const h8_t*)(wp + 8 * m);   // 16B aligned: WSTR%4==0... (8-word step)
            wj[j][8 * m + 0] = __builtin_shufflevector(v, v, 0, 1);
            wj[j][8 * m + 1] = __builtin_shufflevector(v, v, 2, 3);
            wj[j][8 * m + 2] = __builtin_shufflevector(v, v, 4, 5);
            wj[j][8 * m + 3] = __builtin_shufflevector(v, v, 6, 7);
            h8_t v2 = *(const h8_t*)(wp + 8 * m + 4);
            wj[j][8 * m + 4] = __builtin_shufflevector(v2, v2, 0, 1);
            wj[j][8 * m + 5] = __builtin_shufflevector(v2, v2, 2, 3);
            wj[j][8 * m + 6] = __builtin_shufflevector(v2, v2, 4, 5);
            wj[j][8 * m + 7] = __builtin_shufflevector(v2, v2, 6, 7);
        }
    }

    for (int c = 0; c < CC; ++c) {
        __syncthreads();  // previous channel's readers done
        const float* src = img + (size_t)(b * CC + c) * HH * WW;
        for (int f = tid; f < TROWS * TLW; f += 256) {
            int r = f >> 5;            // / TLW
            int w = f & 31;            // % TLW
            int gy = tiley - 15 + r;
            int gx = tilex - 15 + 2 * w;
            float v0 = 0.f, v1 = 0.f;
            if ((unsigned)gy < (unsigned)HH) {
                if ((unsigned)gx < (unsigned)WW) v0 = src[gy * WW + gx];
                if ((unsigned)(gx + 1) < (unsigned)WW) v1 = src[gy * WW + gx + 1];
            }
            h2_t pv; pv.x = (_Float16)v0; pv.y = (_Float16)v1;
            tile[r * TWORDS + w] = pv;
        }
        __syncthreads();

        float acc0 = 0.f, acc1 = 0.f, acc2 = 0.f, acc3 = 0.f;
        const h2_t* rowbase = &tile[ty * TWORDS + 2 * tx];
        #pragma unroll
        for (int dy = 0; dy < KC; ++dy) {
            const h4_t* rp4 = (const h4_t*)(rowbase + dy * TWORDS);  // 8B-aligned
            h2_t rw[18];
            #pragma unroll
            for (int m = 0; m < 9; ++m) {
                h4_t q = rp4[m];                    // ds_read_b64, conflict-free layout
                rw[2 * m]     = __builtin_shufflevector(q, q, 0, 1);  // low VGPR
                rw[2 * m + 1] = __builtin_shufflevector(q, q, 2, 3);  // high VGPR
            }
            float rs0 = 0.f, rs1 = 0.f, rs2 = 0.f, rs3 = 0.f;
            #pragma unroll
            for (int m = 0; m < 16; ++m) {
                rs0 = __builtin_amdgcn_fdot2(wj[0][m], rw[m],     rs0, false);
                rs1 = __builtin_amdgcn_fdot2(wj[1][m], rw[m],     rs1, false);
                rs2 = __builtin_amdgcn_fdot2(wj[2][m], rw[m + 1], rs2, false);
                rs3 = __builtin_amdgcn_fdot2(wj[3][m], rw[m + 1], rs3, false);
            }
            // column taps g[dy] from the same registers (dy unrolled -> static indices)
            float cw0, cw1, cw2, cw3;
            if ((dy & 1) == 0) {
                cw0 = (float)wj[0][dy >> 1].x;           // A: lo = g[dy]
                cw2 = (float)wj[2][dy >> 1].x;
                cw1 = (float)wj[1][dy >> 1].y;           // B: hi = g[dy]
                cw3 = (float)wj[3][dy >> 1].y;
            } else {
                cw0 = (float)wj[0][dy >> 1].y;           // A: hi = g[dy]
                cw2 = (float)wj[2][dy >> 1].y;
                cw1 = (float)wj[1][(dy + 1) >> 1].x;     // B: lo of next word = g[dy]
                cw3 = (float)wj[3][(dy + 1) >> 1].x;
            }
            acc0 += cw0 * rs0;
            acc1 += cw1 * rs1;
            acc2 += cw2 * rs2;
            acc3 += cw3 * rs3;
        }

        *(float4*)&out[((size_t)(b * CC + c) * HH + yo) * WW + xo] =
            make_float4(acc0, acc1, acc2, acc3);
    }
}

extern "C" void kernel_launch(void* const* d_in, const int* in_sizes, int n_in,
                              void* d_out, int out_size, void* d_ws, size_t ws_size,
                              hipStream_t stream) {
    const float* sharp = (const float*)d_in[0];
    const float* cocm  = (const float*)d_in[1];
    float* out = (float*)d_out;

    init_wtab_kernel<<<1, 1024, 0, stream>>>();
    dim3 grid(WW / TXO, HH / TYO, BB);
    dim3 block(8, 32, 1);
    defocus_kernel<<<grid, block, 0, stream>>>(sharp, cocm, out);
}